// Round 1
// baseline (717.944 us; speedup 1.0000x reference)
//
#include <hip/hip_runtime.h>
#include <math.h>

#define NBR    4        // NUM_BRANCHES
#define REP    1024     // REP_DIM
#define FD     128      // FEAT_DIM
#define NDATA  100000
#define KP1    4097     // NCE_K + 1
#define BN     128      // BATCH
#define MPN    0.04096f // m * Pn = 4096 / 100000
#define EPS_C  1e-7f
#define TINV   (1.0f / 0.07f)
#define KSPLIT 4

// ---------------------------------------------------------------------------
// Kernel 1: h[r,b,d] = sum_i emb_r[b,i] * W[r,d,i] + bias[r,d];  e = h/||h||
// grid (NBR, BN), block 128 (one thread per d)
// ---------------------------------------------------------------------------
__global__ void k_feat(const float* __restrict__ e0, const float* __restrict__ e1,
                       const float* __restrict__ e2, const float* __restrict__ e3,
                       const float* __restrict__ W, const float* __restrict__ bias,
                       float* __restrict__ e_out) {
    const int r = blockIdx.x;
    const int b = blockIdx.y;
    const float* emb = (r == 0 ? e0 : r == 1 ? e1 : r == 2 ? e2 : e3) + (size_t)b * REP;

    __shared__ float s_emb[REP];
    for (int i = threadIdx.x; i < REP; i += blockDim.x) s_emb[i] = emb[i];
    __syncthreads();

    const int d = threadIdx.x;  // 0..127
    const float4* wrow = (const float4*)(W + ((size_t)r * FD + d) * REP);
    float acc = 0.f;
#pragma unroll 8
    for (int c = 0; c < REP / 4; ++c) {
        float4 v = wrow[c];
        acc += v.x * s_emb[4*c+0] + v.y * s_emb[4*c+1]
             + v.z * s_emb[4*c+2] + v.w * s_emb[4*c+3];
    }
    float h = acc + bias[r * FD + d];

    __shared__ float red[FD];
    red[d] = h * h;
    __syncthreads();
    for (int off = FD / 2; off > 0; off >>= 1) {
        if (d < off) red[d] += red[d + off];
        __syncthreads();
    }
    float nrm = sqrtf(red[0]);
    e_out[((size_t)r * BN + b) * FD + d] = h / nrm;
}

// ---------------------------------------------------------------------------
// Per-row 4-way dot: row (float4*, 128 floats) vs s_e[i*FD + :] for i=0..3
// ---------------------------------------------------------------------------
static __device__ __forceinline__ void dot4(const float4* __restrict__ row,
                                            const float* __restrict__ se,
                                            float& a0, float& a1, float& a2, float& a3) {
    a0 = a1 = a2 = a3 = 0.f;
#pragma unroll 4
    for (int c = 0; c < FD / 4; ++c) {
        float4 v = row[c];
        const int o = 4 * c;
        a0 += v.x * se[0*FD+o+0] + v.y * se[0*FD+o+1] + v.z * se[0*FD+o+2] + v.w * se[0*FD+o+3];
        a1 += v.x * se[1*FD+o+0] + v.y * se[1*FD+o+1] + v.z * se[1*FD+o+2] + v.w * se[1*FD+o+3];
        a2 += v.x * se[2*FD+o+0] + v.y * se[2*FD+o+1] + v.z * se[2*FD+o+2] + v.w * se[2*FD+o+3];
        a3 += v.x * se[3*FD+o+0] + v.y * se[3*FD+o+1] + v.z * se[3*FD+o+2] + v.w * se[3*FD+o+3];
    }
}

// ---------------------------------------------------------------------------
// Pass 1: for each (j,b,k): row = memory[j, cidx[b,k], :]
//         s_i = dot(row, e[i,b,:]);  ex_i = exp(s_i/T)
//         Zsum[i][j] += ex_i;  optionally store ex as float4 at [j][b][k]
// grid (NBR, BN, KSPLIT), block 256
// ---------------------------------------------------------------------------
template <bool STORE>
__global__ void k_pass1(const float* __restrict__ e, const float* __restrict__ memory,
                        const int* __restrict__ cidx,
                        float* __restrict__ Zsum, float4* __restrict__ expS) {
    const int j = blockIdx.x;
    const int b = blockIdx.y;

    __shared__ float s_e[NBR * FD];
    for (int t = threadIdx.x; t < NBR * FD; t += blockDim.x) {
        int i = t >> 7, d = t & (FD - 1);
        s_e[t] = e[((size_t)i * BN + b) * FD + d];
    }
    __syncthreads();

    const int* ci = cidx + (size_t)b * KP1;
    const float4* mem4 = (const float4*)(memory + (size_t)j * NDATA * FD);
    float z0 = 0.f, z1 = 0.f, z2 = 0.f, z3 = 0.f;

    for (int k = threadIdx.x + blockIdx.z * blockDim.x; k < KP1;
         k += blockDim.x * gridDim.z) {
        const int n = ci[k];
        const float4* row = mem4 + (size_t)n * (FD / 4);
        float a0, a1, a2, a3;
        dot4(row, s_e, a0, a1, a2, a3);
        float x0 = __expf(a0 * TINV);
        float x1 = __expf(a1 * TINV);
        float x2 = __expf(a2 * TINV);
        float x3 = __expf(a3 * TINV);
        z0 += x0; z1 += x1; z2 += x2; z3 += x3;
        if (STORE) {
            float4 st; st.x = x0; st.y = x1; st.z = x2; st.w = x3;
            expS[((size_t)j * BN + b) * KP1 + k] = st;
        }
    }

    __shared__ float sred[256];
    float zs[NBR] = {z0, z1, z2, z3};
    for (int i = 0; i < NBR; ++i) {
        sred[threadIdx.x] = zs[i];
        __syncthreads();
        for (int off = 128; off > 0; off >>= 1) {
            if ((int)threadIdx.x < off) sred[threadIdx.x] += sred[threadIdx.x + off];
            __syncthreads();
        }
        if (threadIdx.x == 0) atomicAdd(&Zsum[i * NBR + j], sred[0]);
        __syncthreads();
    }
}

// ---------------------------------------------------------------------------
// Shared epilogue math:
//   pos term (k==0):  log(pos/(pos+c))     = -log1p(c/pos),        c = MPN+EPS
//   neg term (k>=1):  log(MPN/(neg+c))     = -log1p((neg+EPS)/MPN)
// ---------------------------------------------------------------------------
static __device__ __forceinline__ float term_of(float ex, float zinv, int k) {
    const float c = MPN + EPS_C;
    float v = ex * zinv;  // pos or neg
    if (k == 0) return -log1pf(c / v);
    return -log1pf((v + EPS_C) / MPN);
}

// ---------------------------------------------------------------------------
// Pass 2 (stored path): stream expS back, accumulate per-(i,j) term sums
// grid (NBR, BN, KSPLIT), block 256
// ---------------------------------------------------------------------------
__global__ void k_pass2_stored(const float4* __restrict__ expS,
                               const float* __restrict__ Zsum,
                               float* __restrict__ accum) {
    const int j = blockIdx.x;
    const int b = blockIdx.y;

    __shared__ float s_zinv[NBR];
    if (threadIdx.x < NBR) {
        float Z = Zsum[threadIdx.x * NBR + j] *
                  (float)((double)NDATA / ((double)BN * (double)KP1));
        s_zinv[threadIdx.x] = 1.0f / Z;
    }
    __syncthreads();

    const float4* es = expS + ((size_t)j * BN + b) * KP1;
    float a0 = 0.f, a1 = 0.f, a2 = 0.f, a3 = 0.f;

    for (int k = threadIdx.x + blockIdx.z * blockDim.x; k < KP1;
         k += blockDim.x * gridDim.z) {
        float4 v = es[k];
        a0 += term_of(v.x, s_zinv[0], k);
        a1 += term_of(v.y, s_zinv[1], k);
        a2 += term_of(v.z, s_zinv[2], k);
        a3 += term_of(v.w, s_zinv[3], k);
    }

    __shared__ float sred[256];
    float as[NBR] = {a0, a1, a2, a3};
    for (int i = 0; i < NBR; ++i) {
        sred[threadIdx.x] = as[i];
        __syncthreads();
        for (int off = 128; off > 0; off >>= 1) {
            if ((int)threadIdx.x < off) sred[threadIdx.x] += sred[threadIdx.x + off];
            __syncthreads();
        }
        if (threadIdx.x == 0) atomicAdd(&accum[i * NBR + j], sred[0]);
        __syncthreads();
    }
}

// ---------------------------------------------------------------------------
// Pass 2 (fallback, re-gather): recompute dots, then same epilogue
// ---------------------------------------------------------------------------
__global__ void k_pass2_regather(const float* __restrict__ e, const float* __restrict__ memory,
                                 const int* __restrict__ cidx,
                                 const float* __restrict__ Zsum, float* __restrict__ accum) {
    const int j = blockIdx.x;
    const int b = blockIdx.y;

    __shared__ float s_e[NBR * FD];
    __shared__ float s_zinv[NBR];
    for (int t = threadIdx.x; t < NBR * FD; t += blockDim.x) {
        int i = t >> 7, d = t & (FD - 1);
        s_e[t] = e[((size_t)i * BN + b) * FD + d];
    }
    if (threadIdx.x < NBR) {
        float Z = Zsum[threadIdx.x * NBR + j] *
                  (float)((double)NDATA / ((double)BN * (double)KP1));
        s_zinv[threadIdx.x] = 1.0f / Z;
    }
    __syncthreads();

    const int* ci = cidx + (size_t)b * KP1;
    const float4* mem4 = (const float4*)(memory + (size_t)j * NDATA * FD);
    float a0s = 0.f, a1s = 0.f, a2s = 0.f, a3s = 0.f;

    for (int k = threadIdx.x + blockIdx.z * blockDim.x; k < KP1;
         k += blockDim.x * gridDim.z) {
        const int n = ci[k];
        const float4* row = mem4 + (size_t)n * (FD / 4);
        float a0, a1, a2, a3;
        dot4(row, s_e, a0, a1, a2, a3);
        a0s += term_of(__expf(a0 * TINV), s_zinv[0], k);
        a1s += term_of(__expf(a1 * TINV), s_zinv[1], k);
        a2s += term_of(__expf(a2 * TINV), s_zinv[2], k);
        a3s += term_of(__expf(a3 * TINV), s_zinv[3], k);
    }

    __shared__ float sred[256];
    float as[NBR] = {a0s, a1s, a2s, a3s};
    for (int i = 0; i < NBR; ++i) {
        sred[threadIdx.x] = as[i];
        __syncthreads();
        for (int off = 128; off > 0; off >>= 1) {
            if ((int)threadIdx.x < off) sred[threadIdx.x] += sred[threadIdx.x + off];
            __syncthreads();
        }
        if (threadIdx.x == 0) atomicAdd(&accum[i * NBR + j], sred[0]);
        __syncthreads();
    }
}

// ---------------------------------------------------------------------------
__global__ void k_init(float* __restrict__ p) {
    if (threadIdx.x < 32) p[threadIdx.x] = 0.f;  // Zsum[16] + accum[16]
}

__global__ void k_final(const float* __restrict__ accum, float* __restrict__ out) {
    if (threadIdx.x == 0) {
        float s = 0.f;
        for (int i = 0; i < NBR; ++i)
            for (int j = 0; j < NBR; ++j)
                if (i != j) s += -accum[i * NBR + j] / (float)BN;
        out[0] = s;
    }
}

// ---------------------------------------------------------------------------
extern "C" void kernel_launch(void* const* d_in, const int* in_sizes, int n_in,
                              void* d_out, int out_size, void* d_ws, size_t ws_size,
                              hipStream_t stream) {
    const float* e0   = (const float*)d_in[0];
    const float* e1   = (const float*)d_in[1];
    const float* e2   = (const float*)d_in[2];
    const float* e3   = (const float*)d_in[3];
    const float* W    = (const float*)d_in[4];
    const float* bias = (const float*)d_in[5];
    const float* mem  = (const float*)d_in[6];
    // d_in[7] = idx (unused; contrast_idx[:,0] == idx)
    const int*   cidx = (const int*)d_in[8];
    float* out = (float*)d_out;

    float* ws    = (float*)d_ws;
    float* e     = ws;            // 4*128*128 = 65536 floats
    float* Zsum  = ws + 65536;    // 16 floats
    float* accum = ws + 65552;    // 16 floats
    float4* expS = (float4*)(ws + 65568);  // byte offset 262272, 16B-aligned

    const size_t need_bytes =
        (size_t)65568 * 4 + (size_t)NBR * BN * KP1 * sizeof(float4);
    const bool store = ws_size >= need_bytes;

    k_init<<<1, 64, 0, stream>>>(Zsum);
    k_feat<<<dim3(NBR, BN), 128, 0, stream>>>(e0, e1, e2, e3, W, bias, e);

    dim3 grid(NBR, BN, KSPLIT);
    if (store) {
        k_pass1<true><<<grid, 256, 0, stream>>>(e, mem, cidx, Zsum, expS);
        k_pass2_stored<<<grid, 256, 0, stream>>>(expS, Zsum, accum);
    } else {
        k_pass1<false><<<grid, 256, 0, stream>>>(e, mem, cidx, Zsum, nullptr);
        k_pass2_regather<<<grid, 256, 0, stream>>>(e, mem, cidx, Zsum, accum);
    }
    k_final<<<1, 64, 0, stream>>>(accum, out);
}